// Round 1
// baseline (1063.920 us; speedup 1.0000x reference)
//
#include <hip/hip_runtime.h>
#include <math.h>

// Problem constants (from reference)
#define N_NODES 50000
#define N_EDGES 800000
#define ET (N_EDGES + N_NODES)   // edges + self loops = 850000
#define IN_DIM 128
#define HID 128
#define OUT_DIM 64

__device__ __forceinline__ float lrelu(float x){ return x >= 0.f ? x : 0.2f * x; }
__device__ __forceinline__ float eluf(float x){ return x > 0.f ? x : expm1f(x); }

// ---------------------------------------------------------------------------
// K1: h1 = x @ W1  [N,128]; alpha_src1[n][h] = <h1[n,h,:], a_src1[h,:]>, same dst.
// W1 (64KB) in LDS; 2 nodes per block-iteration, grid-stride.
// ---------------------------------------------------------------------------
__global__ __launch_bounds__(256, 2) void k_gemm1(
    const float* __restrict__ x, const float* __restrict__ W1,
    const float* __restrict__ a_s, const float* __restrict__ a_d,
    float* __restrict__ h1, float* __restrict__ as1, float* __restrict__ ad1)
{
    __shared__ float sW[128 * 128];
    __shared__ float sx[2][128];
    __shared__ float redS[256];
    __shared__ float redD[256];
    const int tid = threadIdx.x;
    for (int i = tid; i < 128 * 128; i += 256) sW[i] = W1[i];
    const int nl = tid >> 7;        // node within pair
    const int j  = tid & 127;       // output channel
    const float asj = a_s[j], adj = a_d[j];
    const int nPairs = (N_NODES + 1) / 2;
    for (int pair = blockIdx.x; pair < nPairs; pair += gridDim.x) {
        const int n0 = pair * 2;
        const int n  = n0 + nl;
        __syncthreads();            // protect sx/redS from previous iteration
        sx[nl][j] = (n < N_NODES) ? x[n * 128 + j] : 0.f;
        __syncthreads();
        float sum = 0.f;
        #pragma unroll
        for (int k = 0; k < 128; k++) sum = fmaf(sx[nl][k], sW[k * 128 + j], sum);
        if (n < N_NODES) h1[n * 128 + j] = sum;
        redS[tid] = sum * asj;
        redD[tid] = sum * adj;
        __syncthreads();
        if (tid < 8) {              // 2 nodes x 4 heads
            const int nl2 = tid >> 2, hd = tid & 3;
            const int base = nl2 * 128 + hd * 32;
            float ss = 0.f, sd = 0.f;
            #pragma unroll
            for (int i = 0; i < 32; i++) { ss += redS[base + i]; sd += redD[base + i]; }
            const int n2 = n0 + nl2;
            if (n2 < N_NODES) { as1[n2 * 4 + hd] = ss; ad1[n2 * 4 + hd] = sd; }
        }
    }
}

// ---------------------------------------------------------------------------
// K2: edge pass A, layer 1: w = exp(leaky_relu(as[s]+ad[d])); denom[d] += w
// ---------------------------------------------------------------------------
__global__ __launch_bounds__(256) void k_edgeA1(
    const int* __restrict__ src, const int* __restrict__ dst,
    const float4* __restrict__ as1, const float4* __restrict__ ad1,
    float4* __restrict__ expE, float* __restrict__ denom)
{
    const int e = blockIdx.x * 256 + threadIdx.x;
    if (e >= ET) return;
    int s, d;
    if (e < N_EDGES) { s = src[e]; d = dst[e]; } else { s = d = e - N_EDGES; }
    const float4 a = as1[s];
    const float4 b = ad1[d];
    float4 w;
    w.x = expf(lrelu(a.x + b.x));
    w.y = expf(lrelu(a.y + b.y));
    w.z = expf(lrelu(a.z + b.z));
    w.w = expf(lrelu(a.w + b.w));
    expE[e] = w;
    atomicAdd(&denom[d * 4 + 0], w.x);
    atomicAdd(&denom[d * 4 + 1], w.y);
    atomicAdd(&denom[d * 4 + 2], w.z);
    atomicAdd(&denom[d * 4 + 3], w.w);
}

// ---------------------------------------------------------------------------
// K3: edge pass B, layer 1: acc1[d,:] += h1[s,:] * (expE[e,h]/denom[d,h])
// 128 lanes per edge (one lane per channel), 2 edges per block.
// ---------------------------------------------------------------------------
__global__ __launch_bounds__(256) void k_edgeB1(
    const int* __restrict__ src, const int* __restrict__ dst,
    const float* __restrict__ expE, const float* __restrict__ denom,
    const float* __restrict__ h1, float* __restrict__ acc1)
{
    const int idx = blockIdx.x * 2 + (threadIdx.x >> 7);
    const int c = threadIdx.x & 127;
    if (idx >= ET) return;
    int s, d;
    if (idx < N_EDGES) { s = src[idx]; d = dst[idx]; } else { s = d = idx - N_EDGES; }
    const int hd = c >> 5;
    const float alpha = expE[idx * 4 + hd] / (denom[d * 4 + hd] + 1e-16f);
    atomicAdd(&acc1[d * 128 + c], h1[s * 128 + c] * alpha);
}

// ---------------------------------------------------------------------------
// K4: hE = elu(acc1 + b1); h2 = hE @ W2 [N,64]; alpha2 via wave reduce.
// W2 (32KB) in LDS; 4 nodes per block-iteration (one wave each), grid-stride.
// ---------------------------------------------------------------------------
__global__ __launch_bounds__(256, 2) void k_layer2(
    const float* __restrict__ acc1, const float* __restrict__ b1,
    const float* __restrict__ W2, const float* __restrict__ a_s2, const float* __restrict__ a_d2,
    float* __restrict__ h2, float* __restrict__ as2, float* __restrict__ ad2)
{
    __shared__ float sW[128 * 64];
    __shared__ float sh[4][128];
    const int tid = threadIdx.x;
    for (int i = tid; i < 128 * 64; i += 256) sW[i] = W2[i];
    const int nl = tid >> 6;   // wave index == node within quad
    const int j  = tid & 63;   // lane == output channel
    const float aj = a_s2[j], dj = a_d2[j];
    const int nQuads = (N_NODES + 3) / 4;
    for (int q = blockIdx.x; q < nQuads; q += gridDim.x) {
        const int n0 = q * 4;
        __syncthreads();
        for (int i = tid; i < 512; i += 256) {
            const int nn = n0 + (i >> 7), c = i & 127;
            float v = 0.f;
            if (nn < N_NODES) v = eluf(acc1[nn * 128 + c] + b1[c]);
            sh[i >> 7][c] = v;
        }
        __syncthreads();
        float sum = 0.f;
        #pragma unroll
        for (int k = 0; k < 128; k++) sum = fmaf(sh[nl][k], sW[k * 64 + j], sum);
        const int n = n0 + nl;
        if (n < N_NODES) h2[n * 64 + j] = sum;
        float ps = sum * aj, pd = sum * dj;
        #pragma unroll
        for (int off = 32; off > 0; off >>= 1) {
            ps += __shfl_xor(ps, off);
            pd += __shfl_xor(pd, off);
        }
        if (j == 0 && n < N_NODES) { as2[n] = ps; ad2[n] = pd; }
    }
}

// ---------------------------------------------------------------------------
// K5: edge pass A, layer 2 (1 head)
// ---------------------------------------------------------------------------
__global__ __launch_bounds__(256) void k_edgeA2(
    const int* __restrict__ src, const int* __restrict__ dst,
    const float* __restrict__ as2, const float* __restrict__ ad2,
    float* __restrict__ expE, float* __restrict__ denom)
{
    const int e = blockIdx.x * 256 + threadIdx.x;
    if (e >= ET) return;
    int s, d;
    if (e < N_EDGES) { s = src[e]; d = dst[e]; } else { s = d = e - N_EDGES; }
    const float w = expf(lrelu(as2[s] + ad2[d]));
    expE[e] = w;
    atomicAdd(&denom[d], w);
}

// ---------------------------------------------------------------------------
// K6: edge pass B, layer 2: acc2[d,:] += h2[s,:] * (expE[e]/denom[d])
// 64 lanes per edge, 4 edges per block.
// ---------------------------------------------------------------------------
__global__ __launch_bounds__(256) void k_edgeB2(
    const int* __restrict__ src, const int* __restrict__ dst,
    const float* __restrict__ expE, const float* __restrict__ denom,
    const float* __restrict__ h2, float* __restrict__ acc2)
{
    const int idx = blockIdx.x * 4 + (threadIdx.x >> 6);
    const int c = threadIdx.x & 63;
    if (idx >= ET) return;
    int s, d;
    if (idx < N_EDGES) { s = src[idx]; d = dst[idx]; } else { s = d = idx - N_EDGES; }
    const float alpha = expE[idx] / (denom[d] + 1e-16f);
    atomicAdd(&acc2[d * 64 + c], h2[s * 64 + c] * alpha);
}

// ---------------------------------------------------------------------------
// K7: o = elu(acc2 + b2); p = relu(o@pw1+pb1); out = p@pw2+pb2
// pw1,pw2 (32KB) in LDS; 4 nodes per block-iteration, grid-stride.
// ---------------------------------------------------------------------------
__global__ __launch_bounds__(256, 2) void k_out(
    const float* __restrict__ acc2, const float* __restrict__ b2,
    const float* __restrict__ pw1, const float* __restrict__ pb1,
    const float* __restrict__ pw2, const float* __restrict__ pb2,
    float* __restrict__ out)
{
    __shared__ float s1[64 * 64];
    __shared__ float s2[64 * 64];
    __shared__ float so[4][64];
    __shared__ float sp[4][64];
    const int tid = threadIdx.x;
    for (int i = tid; i < 4096; i += 256) { s1[i] = pw1[i]; s2[i] = pw2[i]; }
    const int nl = tid >> 6, j = tid & 63;
    const float bb2 = b2[j], pbb1 = pb1[j], pbb2 = pb2[j];
    const int nQuads = (N_NODES + 3) / 4;
    for (int q = blockIdx.x; q < nQuads; q += gridDim.x) {
        const int n = q * 4 + nl;
        __syncthreads();
        so[nl][j] = (n < N_NODES) ? eluf(acc2[n * 64 + j] + bb2) : 0.f;
        __syncthreads();
        float p = pbb1;
        #pragma unroll
        for (int k = 0; k < 64; k++) p = fmaf(so[nl][k], s1[k * 64 + j], p);
        p = fmaxf(p, 0.f);
        sp[nl][j] = p;
        __syncthreads();
        float o = pbb2;
        #pragma unroll
        for (int k = 0; k < 64; k++) o = fmaf(sp[nl][k], s2[k * 64 + j], o);
        if (n < N_NODES) out[n * 64 + j] = o;
    }
}

// ---------------------------------------------------------------------------
extern "C" void kernel_launch(void* const* d_in, const int* in_sizes, int n_in,
                              void* d_out, int out_size, void* d_ws, size_t ws_size,
                              hipStream_t stream)
{
    const float* x      = (const float*)d_in[0];
    const int*   ei     = (const int*)d_in[1];   // [2, E] int32
    const int*   src    = ei;
    const int*   dst    = ei + N_EDGES;
    const float* W1     = (const float*)d_in[2];
    const float* a_src1 = (const float*)d_in[3];
    const float* a_dst1 = (const float*)d_in[4];
    const float* b1     = (const float*)d_in[5];
    const float* W2     = (const float*)d_in[6];
    const float* a_src2 = (const float*)d_in[7];
    const float* a_dst2 = (const float*)d_in[8];
    const float* b2     = (const float*)d_in[9];
    const float* pw1    = (const float*)d_in[10];
    const float* pb1    = (const float*)d_in[11];
    const float* pw2    = (const float*)d_in[12];
    const float* pb2    = (const float*)d_in[13];

    // Workspace layout (floats). Accumulators (zeroed) placed first, contiguous.
    float* ws     = (float*)d_ws;
    float* acc1   = ws;                         // N*128 = 6,400,000
    float* denom1 = acc1   + 6400000;           // N*4   =   200,000
    float* acc2   = denom1 + 200000;            // N*64  = 3,200,000
    float* denom2 = acc2   + 3200000;           // N     =    50,000
    float* h1     = denom2 + 50000;             // N*128 = 6,400,000
    float* as1    = h1     + 6400000;           // N*4
    float* ad1    = as1    + 200000;            // N*4
    float* expE1  = ad1    + 200000;            // ET*4  = 3,400,000
    float* h2     = expE1  + 3400000;           // N*64  = 3,200,000
    float* as2    = h2     + 3200000;           // N
    float* ad2    = as2    + 50000;             // N
    float* expE2  = ad2    + 50000;             // ET    =   850,000
    // total = 24,200,000 floats = 96.8 MB

    // Zero all atomic accumulators in one contiguous memset (capture-safe).
    hipMemsetAsync(acc1, 0, (size_t)9850000 * sizeof(float), stream);

    k_gemm1<<<2048, 256, 0, stream>>>(x, W1, a_src1, a_dst1, h1, as1, ad1);
    k_edgeA1<<<(ET + 255) / 256, 256, 0, stream>>>(src, dst, (const float4*)as1,
                                                   (const float4*)ad1, (float4*)expE1, denom1);
    k_edgeB1<<<(ET + 1) / 2, 256, 0, stream>>>(src, dst, expE1, denom1, h1, acc1);
    k_layer2<<<2048, 256, 0, stream>>>(acc1, b1, W2, a_src2, a_dst2, h2, as2, ad2);
    k_edgeA2<<<(ET + 255) / 256, 256, 0, stream>>>(src, dst, as2, ad2, expE2, denom2);
    k_edgeB2<<<(ET + 3) / 4, 256, 0, stream>>>(src, dst, expE2, denom2, h2, acc2);
    k_out<<<2048, 256, 0, stream>>>(acc2, b2, pw1, pb1, pw2, pb2, (float*)d_out);
}

// Round 2
// 741.409 us; speedup vs baseline: 1.4350x; 1.4350x over previous
//
#include <hip/hip_runtime.h>
#include <math.h>

// Problem constants (from reference)
#define N_NODES 50000
#define N_EDGES 800000
#define ET (N_EDGES + N_NODES)   // edges + self loops = 850000
#define IN_DIM 128
#define HID 128
#define OUT_DIM 64

__device__ __forceinline__ float lrelu(float x){ return x >= 0.f ? x : 0.2f * x; }
__device__ __forceinline__ float eluf(float x){ return x > 0.f ? x : expm1f(x); }

// ---------------------------------------------------------------------------
// CSR build: histogram over dst -> exclusive scan -> scatter src ids.
// ---------------------------------------------------------------------------
__global__ __launch_bounds__(256) void k_hist(const int* __restrict__ dst, int* __restrict__ deg)
{
    const int e = blockIdx.x * 256 + threadIdx.x;
    if (e >= ET) return;
    const int d = (e < N_EDGES) ? dst[e] : (e - N_EDGES);
    atomicAdd(&deg[d], 1);
}

// Single-block scan: 1024 threads, each handles a contiguous chunk of 49.
__global__ __launch_bounds__(1024) void k_scan(const int* __restrict__ deg,
                                               int* __restrict__ rowptr, int* __restrict__ cursor)
{
    __shared__ int part[1024];
    const int t = threadIdx.x;
    const int chunk = (N_NODES + 1023) / 1024;      // 49
    const int lo = t * chunk;
    const int hi = min(lo + chunk, N_NODES);
    int s = 0;
    for (int i = lo; i < hi; i++) s += deg[i];
    part[t] = s;
    __syncthreads();
    // Hillis-Steele inclusive scan
    for (int d = 1; d < 1024; d <<= 1) {
        int add = (t >= d) ? part[t - d] : 0;
        __syncthreads();
        part[t] += add;
        __syncthreads();
    }
    int off = part[t] - s;                          // exclusive prefix
    for (int i = lo; i < hi; i++) {
        rowptr[i] = off; cursor[i] = off;
        off += deg[i];
    }
    if (t == 1023) rowptr[N_NODES] = off;           // == ET
}

__global__ __launch_bounds__(256) void k_scatter(const int* __restrict__ src,
                                                 const int* __restrict__ dst,
                                                 int* __restrict__ cursor,
                                                 int* __restrict__ csr_src)
{
    const int e = blockIdx.x * 256 + threadIdx.x;
    if (e >= ET) return;
    int s, d;
    if (e < N_EDGES) { s = src[e]; d = dst[e]; } else { s = d = e - N_EDGES; }
    const int pos = atomicAdd(&cursor[d], 1);
    csr_src[pos] = s;
}

// ---------------------------------------------------------------------------
// K1: h1 = x @ W1  [N,128]; alpha_src1[n][h] = <h1[n,h,:], a_src1[h,:]>, same dst.
// W1 (64KB) in LDS; 2 nodes per block-iteration, grid-stride.
// ---------------------------------------------------------------------------
__global__ __launch_bounds__(256, 2) void k_gemm1(
    const float* __restrict__ x, const float* __restrict__ W1,
    const float* __restrict__ a_s, const float* __restrict__ a_d,
    float* __restrict__ h1, float* __restrict__ as1, float* __restrict__ ad1)
{
    __shared__ float sW[128 * 128];
    __shared__ float sx[2][128];
    __shared__ float redS[256];
    __shared__ float redD[256];
    const int tid = threadIdx.x;
    for (int i = tid; i < 128 * 128; i += 256) sW[i] = W1[i];
    const int nl = tid >> 7;        // node within pair
    const int j  = tid & 127;       // output channel
    const float asj = a_s[j], adj = a_d[j];
    const int nPairs = (N_NODES + 1) / 2;
    for (int pair = blockIdx.x; pair < nPairs; pair += gridDim.x) {
        const int n0 = pair * 2;
        const int n  = n0 + nl;
        __syncthreads();            // protect sx/redS from previous iteration
        sx[nl][j] = (n < N_NODES) ? x[n * 128 + j] : 0.f;
        __syncthreads();
        float sum = 0.f;
        #pragma unroll
        for (int k = 0; k < 128; k++) sum = fmaf(sx[nl][k], sW[k * 128 + j], sum);
        if (n < N_NODES) h1[n * 128 + j] = sum;
        redS[tid] = sum * asj;
        redD[tid] = sum * adj;
        __syncthreads();
        if (tid < 8) {              // 2 nodes x 4 heads
            const int nl2 = tid >> 2, hd = tid & 3;
            const int base = nl2 * 128 + hd * 32;
            float ss = 0.f, sd = 0.f;
            #pragma unroll
            for (int i = 0; i < 32; i++) { ss += redS[base + i]; sd += redD[base + i]; }
            const int n2 = n0 + nl2;
            if (n2 < N_NODES) { as1[n2 * 4 + hd] = ss; ad1[n2 * 4 + hd] = sd; }
        }
    }
}

// ---------------------------------------------------------------------------
// Aggregation layer 1: atomic-free. One node per 128 threads (2 nodes/block).
// Thread = channel c; head hd = c>>5. Each thread walks the node's CSR row,
// recomputes w in-register (redundant across the 32 threads of a head; exp is
// cheap), accumulates denom + weighted sum, writes once. No LDS, no barriers.
// ---------------------------------------------------------------------------
__global__ __launch_bounds__(256) void k_aggr1(
    const int* __restrict__ rowptr, const int* __restrict__ csr_src,
    const float* __restrict__ as1, const float* __restrict__ ad1,
    const float* __restrict__ h1, float* __restrict__ acc1)
{
    const int d = blockIdx.x * 2 + (threadIdx.x >> 7);
    const int c = threadIdx.x & 127;
    if (d >= N_NODES) return;
    const int hd = c >> 5;
    const int r0 = rowptr[d], r1 = rowptr[d + 1];
    const float adv = ad1[d * 4 + hd];
    float den = 0.f, acc = 0.f;
    for (int i = r0; i < r1; i++) {
        const int s = csr_src[i];
        const float w = expf(lrelu(as1[s * 4 + hd] + adv));
        den += w;
        acc = fmaf(h1[s * 128 + c], w, acc);
    }
    acc1[d * 128 + c] = acc / (den + 1e-16f);
}

// ---------------------------------------------------------------------------
// K4: hE = elu(acc1 + b1); h2 = hE @ W2 [N,64]; alpha2 via wave reduce.
// W2 (32KB) in LDS; 4 nodes per block-iteration (one wave each), grid-stride.
// ---------------------------------------------------------------------------
__global__ __launch_bounds__(256, 2) void k_layer2(
    const float* __restrict__ acc1, const float* __restrict__ b1,
    const float* __restrict__ W2, const float* __restrict__ a_s2, const float* __restrict__ a_d2,
    float* __restrict__ h2, float* __restrict__ as2, float* __restrict__ ad2)
{
    __shared__ float sW[128 * 64];
    __shared__ float sh[4][128];
    const int tid = threadIdx.x;
    for (int i = tid; i < 128 * 64; i += 256) sW[i] = W2[i];
    const int nl = tid >> 6;   // wave index == node within quad
    const int j  = tid & 63;   // lane == output channel
    const float aj = a_s2[j], dj = a_d2[j];
    const int nQuads = (N_NODES + 3) / 4;
    for (int q = blockIdx.x; q < nQuads; q += gridDim.x) {
        const int n0 = q * 4;
        __syncthreads();
        for (int i = tid; i < 512; i += 256) {
            const int nn = n0 + (i >> 7), c = i & 127;
            float v = 0.f;
            if (nn < N_NODES) v = eluf(acc1[nn * 128 + c] + b1[c]);
            sh[i >> 7][c] = v;
        }
        __syncthreads();
        float sum = 0.f;
        #pragma unroll
        for (int k = 0; k < 128; k++) sum = fmaf(sh[nl][k], sW[k * 64 + j], sum);
        const int n = n0 + nl;
        if (n < N_NODES) h2[n * 64 + j] = sum;
        float ps = sum * aj, pd = sum * dj;
        #pragma unroll
        for (int off = 32; off > 0; off >>= 1) {
            ps += __shfl_xor(ps, off);
            pd += __shfl_xor(pd, off);
        }
        if (j == 0 && n < N_NODES) { as2[n] = ps; ad2[n] = pd; }
    }
}

// ---------------------------------------------------------------------------
// Aggregation layer 2 (1 head): one node per wave (64 threads), 4 nodes/block.
// ---------------------------------------------------------------------------
__global__ __launch_bounds__(256) void k_aggr2(
    const int* __restrict__ rowptr, const int* __restrict__ csr_src,
    const float* __restrict__ as2, const float* __restrict__ ad2,
    const float* __restrict__ h2, float* __restrict__ acc2)
{
    const int d = blockIdx.x * 4 + (threadIdx.x >> 6);
    const int c = threadIdx.x & 63;
    if (d >= N_NODES) return;
    const int r0 = rowptr[d], r1 = rowptr[d + 1];
    const float adv = ad2[d];
    float den = 0.f, acc = 0.f;
    for (int i = r0; i < r1; i++) {
        const int s = csr_src[i];
        const float w = expf(lrelu(as2[s] + adv));
        den += w;
        acc = fmaf(h2[s * 64 + c], w, acc);
    }
    acc2[d * 64 + c] = acc / (den + 1e-16f);
}

// ---------------------------------------------------------------------------
// K7: o = elu(acc2 + b2); p = relu(o@pw1+pb1); out = p@pw2+pb2
// pw1,pw2 (32KB) in LDS; 4 nodes per block-iteration, grid-stride.
// ---------------------------------------------------------------------------
__global__ __launch_bounds__(256, 2) void k_out(
    const float* __restrict__ acc2, const float* __restrict__ b2,
    const float* __restrict__ pw1, const float* __restrict__ pb1,
    const float* __restrict__ pw2, const float* __restrict__ pb2,
    float* __restrict__ out)
{
    __shared__ float s1[64 * 64];
    __shared__ float s2[64 * 64];
    __shared__ float so[4][64];
    __shared__ float sp[4][64];
    const int tid = threadIdx.x;
    for (int i = tid; i < 4096; i += 256) { s1[i] = pw1[i]; s2[i] = pw2[i]; }
    const int nl = tid >> 6, j = tid & 63;
    const float bb2 = b2[j], pbb1 = pb1[j], pbb2 = pb2[j];
    const int nQuads = (N_NODES + 3) / 4;
    for (int q = blockIdx.x; q < nQuads; q += gridDim.x) {
        const int n = q * 4 + nl;
        __syncthreads();
        so[nl][j] = (n < N_NODES) ? eluf(acc2[n * 64 + j] + bb2) : 0.f;
        __syncthreads();
        float p = pbb1;
        #pragma unroll
        for (int k = 0; k < 64; k++) p = fmaf(so[nl][k], s1[k * 64 + j], p);
        p = fmaxf(p, 0.f);
        sp[nl][j] = p;
        __syncthreads();
        float o = pbb2;
        #pragma unroll
        for (int k = 0; k < 64; k++) o = fmaf(sp[nl][k], s2[k * 64 + j], o);
        if (n < N_NODES) out[n * 64 + j] = o;
    }
}

// ---------------------------------------------------------------------------
extern "C" void kernel_launch(void* const* d_in, const int* in_sizes, int n_in,
                              void* d_out, int out_size, void* d_ws, size_t ws_size,
                              hipStream_t stream)
{
    const float* x      = (const float*)d_in[0];
    const int*   ei     = (const int*)d_in[1];   // [2, E] int32
    const int*   src    = ei;
    const int*   dst    = ei + N_EDGES;
    const float* W1     = (const float*)d_in[2];
    const float* a_src1 = (const float*)d_in[3];
    const float* a_dst1 = (const float*)d_in[4];
    const float* b1     = (const float*)d_in[5];
    const float* W2     = (const float*)d_in[6];
    const float* a_src2 = (const float*)d_in[7];
    const float* a_dst2 = (const float*)d_in[8];
    const float* b2     = (const float*)d_in[9];
    const float* pw1    = (const float*)d_in[10];
    const float* pb1    = (const float*)d_in[11];
    const float* pw2    = (const float*)d_in[12];
    const float* pb2    = (const float*)d_in[13];

    // Workspace layout.
    int* deg     = (int*)d_ws;            // 50,000
    int* rowptr  = deg + 50000;           // 50,001
    int* cursor  = rowptr + 50001;        // 50,000
    int* csr_src = cursor + 50000;        // 850,000
    float* fws   = (float*)(csr_src + 850000);
    float* h1    = fws;                   // N*128 = 6,400,000
    float* as1   = h1  + 6400000;         // N*4
    float* ad1   = as1 + 200000;          // N*4
    float* acc1  = ad1 + 200000;          // N*128 = 6,400,000
    float* h2    = acc1 + 6400000;        // N*64  = 3,200,000
    float* as2   = h2  + 3200000;         // N
    float* ad2   = as2 + 50000;           // N
    float* acc2  = ad2 + 50000;           // N*64  = 3,200,000
    // ints: 1,000,051 (4.0 MB) + floats: 19,700,000 (78.8 MB) ~ 82.8 MB

    // CSR build (reused by both layers)
    hipMemsetAsync(deg, 0, 50000 * sizeof(int), stream);
    k_hist<<<(ET + 255) / 256, 256, 0, stream>>>(dst, deg);
    k_scan<<<1, 1024, 0, stream>>>(deg, rowptr, cursor);
    k_scatter<<<(ET + 255) / 256, 256, 0, stream>>>(src, dst, cursor, csr_src);

    // Layer 1
    k_gemm1<<<2048, 256, 0, stream>>>(x, W1, a_src1, a_dst1, h1, as1, ad1);
    k_aggr1<<<(N_NODES + 1) / 2, 256, 0, stream>>>(rowptr, csr_src, as1, ad1, h1, acc1);

    // Layer 2
    k_layer2<<<2048, 256, 0, stream>>>(acc1, b1, W2, a_src2, a_dst2, h2, as2, ad2);
    k_aggr2<<<(N_NODES + 3) / 4, 256, 0, stream>>>(rowptr, csr_src, as2, ad2, h2, acc2);

    // Output MLP
    k_out<<<2048, 256, 0, stream>>>(acc2, b2, pw1, pb1, pw2, pb2, (float*)d_out);
}

// Round 3
// 480.748 us; speedup vs baseline: 2.2131x; 1.5422x over previous
//
#include <hip/hip_runtime.h>
#include <math.h>

// Problem constants (from reference)
#define N_NODES 50000
#define N_EDGES 800000
#define ET (N_EDGES + N_NODES)   // edges + self loops = 850000
#define IN_DIM 128
#define HID 128
#define OUT_DIM 64

__device__ __forceinline__ float lrelu(float x){ return x >= 0.f ? x : 0.2f * x; }
__device__ __forceinline__ float eluf(float x){ return x > 0.f ? x : expm1f(x); }
// RNE float->bf16 (finite inputs)
__device__ __forceinline__ unsigned f2bf(float f){
    unsigned u = __float_as_uint(f);
    return (u + 0x7fffu + ((u >> 16) & 1u)) >> 16;
}
__device__ __forceinline__ float bflo(unsigned u){ return __uint_as_float(u << 16); }
__device__ __forceinline__ float bfhi(unsigned u){ return __uint_as_float(u & 0xffff0000u); }

// ---------------------------------------------------------------------------
// CSR build: histogram over dst -> exclusive scan -> scatter src ids.
// ---------------------------------------------------------------------------
__global__ __launch_bounds__(256) void k_hist(const int* __restrict__ dst, int* __restrict__ deg)
{
    const int e = blockIdx.x * 256 + threadIdx.x;
    if (e >= ET) return;
    const int d = (e < N_EDGES) ? dst[e] : (e - N_EDGES);
    atomicAdd(&deg[d], 1);
}

__global__ __launch_bounds__(1024) void k_scan(const int* __restrict__ deg,
                                               int* __restrict__ rowptr, int* __restrict__ cursor)
{
    __shared__ int part[1024];
    const int t = threadIdx.x;
    const int chunk = (N_NODES + 1023) / 1024;      // 49
    const int lo = t * chunk;
    const int hi = min(lo + chunk, N_NODES);
    int s = 0;
    for (int i = lo; i < hi; i++) s += deg[i];
    part[t] = s;
    __syncthreads();
    for (int d = 1; d < 1024; d <<= 1) {
        int add = (t >= d) ? part[t - d] : 0;
        __syncthreads();
        part[t] += add;
        __syncthreads();
    }
    int off = part[t] - s;                          // exclusive prefix
    for (int i = lo; i < hi; i++) {
        rowptr[i] = off; cursor[i] = off;
        off += deg[i];
    }
    if (t == 1023) rowptr[N_NODES] = off;           // == ET
}

__global__ __launch_bounds__(256) void k_scatter(const int* __restrict__ src,
                                                 const int* __restrict__ dst,
                                                 int* __restrict__ cursor,
                                                 int* __restrict__ csr_src)
{
    const int e = blockIdx.x * 256 + threadIdx.x;
    if (e >= ET) return;
    int s, d;
    if (e < N_EDGES) { s = src[e]; d = dst[e]; } else { s = d = e - N_EDGES; }
    const int pos = atomicAdd(&cursor[d], 1);
    csr_src[pos] = s;
}

// ---------------------------------------------------------------------------
// K1: h1 = x @ W1 [N,128] stored as bf16 (only the gather consumes it);
// attention logits as1/ad1 in fp32. 8 nodes / 256-thread block iteration;
// 32 threads per node, 4 channels each, float4 LDS reads of W1.
// ---------------------------------------------------------------------------
__global__ __launch_bounds__(256, 2) void k_gemm1(
    const float* __restrict__ x, const float* __restrict__ W1,
    const float* __restrict__ a_s, const float* __restrict__ a_d,
    unsigned* __restrict__ h1b /* bf16 packed, uint2 view */,
    float* __restrict__ as1, float* __restrict__ ad1)
{
    __shared__ float sW[128 * 128];   // 64 KB
    __shared__ float sx[8][128];      // 4 KB
    const int tid = threadIdx.x;
    for (int i = tid; i < 4096; i += 256) ((float4*)sW)[i] = ((const float4*)W1)[i];
    const int nl = tid >> 5;          // node 0..7
    const int t  = tid & 31;          // 4-channel group: channels 4t..4t+3
    const float4 as4 = ((const float4*)a_s)[t];
    const float4 ad4 = ((const float4*)a_d)[t];
    const int nGroups = N_NODES / 8;  // 6250 exact
    for (int g = blockIdx.x; g < nGroups; g += gridDim.x) {
        const int n0 = g * 8;
        __syncthreads();
        {
            const int node = tid >> 5, quad = tid & 31;
            float4 v = ((const float4*)x)[(n0 + node) * 32 + quad];
            *(float4*)&sx[node][4 * quad] = v;
        }
        __syncthreads();
        float4 sum = {0.f, 0.f, 0.f, 0.f};
        #pragma unroll
        for (int k = 0; k < 128; k++) {
            const float xv = sx[nl][k];
            const float4 w = *(const float4*)&sW[k * 128 + 4 * t];
            sum.x = fmaf(xv, w.x, sum.x);
            sum.y = fmaf(xv, w.y, sum.y);
            sum.z = fmaf(xv, w.z, sum.z);
            sum.w = fmaf(xv, w.w, sum.w);
        }
        const int n = n0 + nl;
        uint2 pk;
        pk.x = f2bf(sum.x) | (f2bf(sum.y) << 16);
        pk.y = f2bf(sum.z) | (f2bf(sum.w) << 16);
        ((uint2*)h1b)[n * 32 + t] = pk;
        float ps = sum.x * as4.x + sum.y * as4.y + sum.z * as4.z + sum.w * as4.w;
        float pd = sum.x * ad4.x + sum.y * ad4.y + sum.z * ad4.z + sum.w * ad4.w;
        #pragma unroll
        for (int off = 1; off < 8; off <<= 1) {
            ps += __shfl_xor(ps, off);
            pd += __shfl_xor(pd, off);
        }
        if ((t & 7) == 0) {
            as1[n * 4 + (t >> 3)] = ps;
            ad1[n * 4 + (t >> 3)] = pd;
        }
    }
}

// ---------------------------------------------------------------------------
// Aggregation layer 1: atomic-free, bf16 gather table, 64 threads/node
// (2 channels per thread via uint), edge loop unrolled x4 for MLP.
// ---------------------------------------------------------------------------
__global__ __launch_bounds__(256) void k_aggr1(
    const int* __restrict__ rowptr, const int* __restrict__ csr_src,
    const float* __restrict__ as1, const float* __restrict__ ad1,
    const unsigned* __restrict__ h1u, float* __restrict__ acc1)
{
    const int d  = blockIdx.x * 4 + (threadIdx.x >> 6);
    const int c2 = threadIdx.x & 63;    // channels 2*c2, 2*c2+1
    const int hd = c2 >> 4;
    const int r0 = rowptr[d], r1 = rowptr[d + 1];
    const float adv = ad1[d * 4 + hd];
    float den = 0.f, alo = 0.f, ahi = 0.f;
    int i = r0;
    for (; i + 4 <= r1; i += 4) {
        const int s0 = csr_src[i + 0], s1 = csr_src[i + 1];
        const int s2 = csr_src[i + 2], s3 = csr_src[i + 3];
        const float e0 = as1[s0 * 4 + hd], e1 = as1[s1 * 4 + hd];
        const float e2 = as1[s2 * 4 + hd], e3 = as1[s3 * 4 + hd];
        const unsigned u0 = h1u[s0 * 64 + c2], u1 = h1u[s1 * 64 + c2];
        const unsigned u2 = h1u[s2 * 64 + c2], u3 = h1u[s3 * 64 + c2];
        const float w0 = expf(lrelu(e0 + adv));
        const float w1 = expf(lrelu(e1 + adv));
        const float w2 = expf(lrelu(e2 + adv));
        const float w3 = expf(lrelu(e3 + adv));
        den += (w0 + w1) + (w2 + w3);
        alo = fmaf(bflo(u0), w0, alo); ahi = fmaf(bfhi(u0), w0, ahi);
        alo = fmaf(bflo(u1), w1, alo); ahi = fmaf(bfhi(u1), w1, ahi);
        alo = fmaf(bflo(u2), w2, alo); ahi = fmaf(bfhi(u2), w2, ahi);
        alo = fmaf(bflo(u3), w3, alo); ahi = fmaf(bfhi(u3), w3, ahi);
    }
    for (; i < r1; i++) {
        const int s = csr_src[i];
        const float w = expf(lrelu(as1[s * 4 + hd] + adv));
        const unsigned u = h1u[s * 64 + c2];
        den += w;
        alo = fmaf(bflo(u), w, alo);
        ahi = fmaf(bfhi(u), w, ahi);
    }
    const float inv = 1.f / (den + 1e-16f);
    *(float2*)&acc1[d * 128 + 2 * c2] = make_float2(alo * inv, ahi * inv);
}

// ---------------------------------------------------------------------------
// K4: hE = elu(acc1+b1); h2 = hE @ W2 [N,64] stored bf16; logits as2/ad2 fp32.
// 16 nodes / block iteration; 16 threads per node, 4 channels each.
// ---------------------------------------------------------------------------
__global__ __launch_bounds__(256, 2) void k_layer2(
    const float* __restrict__ acc1, const float* __restrict__ b1,
    const float* __restrict__ W2, const float* __restrict__ a_s2, const float* __restrict__ a_d2,
    unsigned* __restrict__ h2b, float* __restrict__ as2, float* __restrict__ ad2)
{
    __shared__ float sW[128 * 64];    // 32 KB
    __shared__ float sh[16][128];     // 8 KB
    const int tid = threadIdx.x;
    for (int i = tid; i < 2048; i += 256) ((float4*)sW)[i] = ((const float4*)W2)[i];
    const int nl = tid >> 4;          // node 0..15
    const int t  = tid & 15;          // channels 4t..4t+3
    const float4 as4 = ((const float4*)a_s2)[t];
    const float4 ad4 = ((const float4*)a_d2)[t];
    const int nGroups = N_NODES / 16; // 3125 exact
    for (int g = blockIdx.x; g < nGroups; g += gridDim.x) {
        const int n0 = g * 16;
        __syncthreads();
        #pragma unroll
        for (int i = tid; i < 512; i += 256) {
            const int node = i >> 5, quad = i & 31;
            float4 v = ((const float4*)acc1)[(n0 + node) * 32 + quad];
            const float4 bb = ((const float4*)b1)[quad];
            v.x = eluf(v.x + bb.x);
            v.y = eluf(v.y + bb.y);
            v.z = eluf(v.z + bb.z);
            v.w = eluf(v.w + bb.w);
            *(float4*)&sh[node][4 * quad] = v;
        }
        __syncthreads();
        float4 sum = {0.f, 0.f, 0.f, 0.f};
        #pragma unroll
        for (int k = 0; k < 128; k++) {
            const float xv = sh[nl][k];
            const float4 w = *(const float4*)&sW[k * 64 + 4 * t];
            sum.x = fmaf(xv, w.x, sum.x);
            sum.y = fmaf(xv, w.y, sum.y);
            sum.z = fmaf(xv, w.z, sum.z);
            sum.w = fmaf(xv, w.w, sum.w);
        }
        const int n = n0 + nl;
        uint2 pk;
        pk.x = f2bf(sum.x) | (f2bf(sum.y) << 16);
        pk.y = f2bf(sum.z) | (f2bf(sum.w) << 16);
        ((uint2*)h2b)[n * 16 + t] = pk;
        float ps = sum.x * as4.x + sum.y * as4.y + sum.z * as4.z + sum.w * as4.w;
        float pd = sum.x * ad4.x + sum.y * ad4.y + sum.z * ad4.z + sum.w * ad4.w;
        #pragma unroll
        for (int off = 1; off < 16; off <<= 1) {
            ps += __shfl_xor(ps, off);
            pd += __shfl_xor(pd, off);
        }
        if (t == 0) { as2[n] = ps; ad2[n] = pd; }
    }
}

// ---------------------------------------------------------------------------
// Aggregation layer 2 (1 head): 32 threads/node (2 bf16 ch per thread).
// ---------------------------------------------------------------------------
__global__ __launch_bounds__(256) void k_aggr2(
    const int* __restrict__ rowptr, const int* __restrict__ csr_src,
    const float* __restrict__ as2, const float* __restrict__ ad2,
    const unsigned* __restrict__ h2u, float* __restrict__ acc2)
{
    const int d  = blockIdx.x * 8 + (threadIdx.x >> 5);
    const int c2 = threadIdx.x & 31;
    const int r0 = rowptr[d], r1 = rowptr[d + 1];
    const float adv = ad2[d];
    float den = 0.f, alo = 0.f, ahi = 0.f;
    int i = r0;
    for (; i + 4 <= r1; i += 4) {
        const int s0 = csr_src[i + 0], s1 = csr_src[i + 1];
        const int s2 = csr_src[i + 2], s3 = csr_src[i + 3];
        const float e0 = as2[s0], e1 = as2[s1], e2 = as2[s2], e3 = as2[s3];
        const unsigned u0 = h2u[s0 * 32 + c2], u1 = h2u[s1 * 32 + c2];
        const unsigned u2 = h2u[s2 * 32 + c2], u3 = h2u[s3 * 32 + c2];
        const float w0 = expf(lrelu(e0 + adv));
        const float w1 = expf(lrelu(e1 + adv));
        const float w2 = expf(lrelu(e2 + adv));
        const float w3 = expf(lrelu(e3 + adv));
        den += (w0 + w1) + (w2 + w3);
        alo = fmaf(bflo(u0), w0, alo); ahi = fmaf(bfhi(u0), w0, ahi);
        alo = fmaf(bflo(u1), w1, alo); ahi = fmaf(bfhi(u1), w1, ahi);
        alo = fmaf(bflo(u2), w2, alo); ahi = fmaf(bfhi(u2), w2, ahi);
        alo = fmaf(bflo(u3), w3, alo); ahi = fmaf(bfhi(u3), w3, ahi);
    }
    for (; i < r1; i++) {
        const int s = csr_src[i];
        const float w = expf(lrelu(as2[s] + adv));
        const unsigned u = h2u[s * 32 + c2];
        den += w;
        alo = fmaf(bflo(u), w, alo);
        ahi = fmaf(bfhi(u), w, ahi);
    }
    const float inv = 1.f / (den + 1e-16f);
    *(float2*)&acc2[d * 64 + 2 * c2] = make_float2(alo * inv, ahi * inv);
}

// ---------------------------------------------------------------------------
// K7: o = elu(acc2+b2); p = relu(o@pw1+pb1); out = p@pw2+pb2.
// 16 nodes / block iteration; 16 threads/node, 4 channels each, float4 LDS.
// ---------------------------------------------------------------------------
__global__ __launch_bounds__(256, 2) void k_out(
    const float* __restrict__ acc2, const float* __restrict__ b2,
    const float* __restrict__ pw1, const float* __restrict__ pb1,
    const float* __restrict__ pw2, const float* __restrict__ pb2,
    float* __restrict__ out)
{
    __shared__ float s1[64 * 64];
    __shared__ float s2[64 * 64];
    __shared__ float so[16][64];
    __shared__ float sp[16][64];
    const int tid = threadIdx.x;
    for (int i = tid; i < 1024; i += 256) {
        ((float4*)s1)[i] = ((const float4*)pw1)[i];
        ((float4*)s2)[i] = ((const float4*)pw2)[i];
    }
    const int nl = tid >> 4, t = tid & 15;
    const float4 b2_4  = ((const float4*)b2)[t];
    const float4 pb1_4 = ((const float4*)pb1)[t];
    const float4 pb2_4 = ((const float4*)pb2)[t];
    const int nGroups = N_NODES / 16;   // 3125
    for (int g = blockIdx.x; g < nGroups; g += gridDim.x) {
        const int n = g * 16 + nl;
        __syncthreads();
        {
            float4 v = ((const float4*)acc2)[n * 16 + t];
            v.x = eluf(v.x + b2_4.x);
            v.y = eluf(v.y + b2_4.y);
            v.z = eluf(v.z + b2_4.z);
            v.w = eluf(v.w + b2_4.w);
            *(float4*)&so[nl][4 * t] = v;
        }
        __syncthreads();
        float4 p = pb1_4;
        #pragma unroll
        for (int k = 0; k < 64; k++) {
            const float xv = so[nl][k];
            const float4 w = *(const float4*)&s1[k * 64 + 4 * t];
            p.x = fmaf(xv, w.x, p.x);
            p.y = fmaf(xv, w.y, p.y);
            p.z = fmaf(xv, w.z, p.z);
            p.w = fmaf(xv, w.w, p.w);
        }
        p.x = fmaxf(p.x, 0.f); p.y = fmaxf(p.y, 0.f);
        p.z = fmaxf(p.z, 0.f); p.w = fmaxf(p.w, 0.f);
        *(float4*)&sp[nl][4 * t] = p;
        __syncthreads();
        float4 o = pb2_4;
        #pragma unroll
        for (int k = 0; k < 64; k++) {
            const float xv = sp[nl][k];
            const float4 w = *(const float4*)&s2[k * 64 + 4 * t];
            o.x = fmaf(xv, w.x, o.x);
            o.y = fmaf(xv, w.y, o.y);
            o.z = fmaf(xv, w.z, o.z);
            o.w = fmaf(xv, w.w, o.w);
        }
        ((float4*)out)[n * 16 + t] = o;
    }
}

// ---------------------------------------------------------------------------
extern "C" void kernel_launch(void* const* d_in, const int* in_sizes, int n_in,
                              void* d_out, int out_size, void* d_ws, size_t ws_size,
                              hipStream_t stream)
{
    const float* x      = (const float*)d_in[0];
    const int*   ei     = (const int*)d_in[1];   // [2, E] int32
    const int*   src    = ei;
    const int*   dst    = ei + N_EDGES;
    const float* W1     = (const float*)d_in[2];
    const float* a_src1 = (const float*)d_in[3];
    const float* a_dst1 = (const float*)d_in[4];
    const float* b1     = (const float*)d_in[5];
    const float* W2     = (const float*)d_in[6];
    const float* a_src2 = (const float*)d_in[7];
    const float* a_dst2 = (const float*)d_in[8];
    const float* b2     = (const float*)d_in[9];
    const float* pw1    = (const float*)d_in[10];
    const float* pb1    = (const float*)d_in[11];
    const float* pw2    = (const float*)d_in[12];
    const float* pb2    = (const float*)d_in[13];

    // Workspace layout.
    int* deg     = (int*)d_ws;            // 50,000
    int* rowptr  = deg + 50000;           // 50,001
    int* cursor  = rowptr + 50001;        // 50,000
    int* csr_src = cursor + 50000;        // 850,000
    unsigned* h1b = (unsigned*)(csr_src + 850000);  // N*64 uints (bf16 x2) = 3,200,000
    unsigned* h2b = h1b + 3200000;                  // N*32 uints           = 1,600,000
    float* fws   = (float*)(h2b + 1600000);
    float* as1   = fws;                   // N*4
    float* ad1   = as1 + 200000;          // N*4
    float* acc1  = ad1 + 200000;          // N*128 = 6,400,000
    float* as2   = acc1 + 6400000;        // N
    float* ad2   = as2 + 50000;           // N
    float* acc2  = ad2 + 50000;           // N*64  = 3,200,000
    // total ~ 62 MB

    // CSR build (reused by both layers)
    hipMemsetAsync(deg, 0, 50000 * sizeof(int), stream);
    k_hist<<<(ET + 255) / 256, 256, 0, stream>>>(dst, deg);
    k_scan<<<1, 1024, 0, stream>>>(deg, rowptr, cursor);
    k_scatter<<<(ET + 255) / 256, 256, 0, stream>>>(src, dst, cursor, csr_src);

    // Layer 1
    k_gemm1<<<2048, 256, 0, stream>>>(x, W1, a_src1, a_dst1, h1b, as1, ad1);
    k_aggr1<<<N_NODES / 4, 256, 0, stream>>>(rowptr, csr_src, as1, ad1, h1b, acc1);

    // Layer 2
    k_layer2<<<2048, 256, 0, stream>>>(acc1, b1, W2, a_src2, a_dst2, h2b, as2, ad2);
    k_aggr2<<<N_NODES / 8, 256, 0, stream>>>(rowptr, csr_src, as2, ad2, h2b, acc2);

    // Output MLP
    k_out<<<2048, 256, 0, stream>>>(acc2, b2, pw1, pb1, pw2, pb2, (float*)d_out);
}

// Round 4
// 372.844 us; speedup vs baseline: 2.8535x; 1.2894x over previous
//
#include <hip/hip_runtime.h>
#include <math.h>

// Problem constants (from reference)
#define N_NODES 50000
#define N_EDGES 800000
#define ET (N_EDGES + N_NODES)   // edges + self loops = 850000
#define IN_DIM 128
#define HID 128
#define OUT_DIM 64
#define SCAN_NB ((N_NODES + 255) / 256)   // 196 scan blocks

__device__ __forceinline__ float lrelu(float x){ return x >= 0.f ? x : 0.2f * x; }
__device__ __forceinline__ float eluf(float x){ return x > 0.f ? x : expm1f(x); }
// RNE float->bf16 (finite inputs)
__device__ __forceinline__ unsigned f2bf(float f){
    unsigned u = __float_as_uint(f);
    return (u + 0x7fffu + ((u >> 16) & 1u)) >> 16;
}
__device__ __forceinline__ float bflo(unsigned u){ return __uint_as_float(u << 16); }
__device__ __forceinline__ float bfhi(unsigned u){ return __uint_as_float(u & 0xffff0000u); }

// ---------------------------------------------------------------------------
// CSR build: histogram -> hierarchical 3-phase scan -> scatter.
// ---------------------------------------------------------------------------
__global__ __launch_bounds__(256) void k_hist(const int* __restrict__ dst, int* __restrict__ deg)
{
    const int e = blockIdx.x * 256 + threadIdx.x;
    if (e >= ET) return;
    const int d = (e < N_EDGES) ? dst[e] : (e - N_EDGES);
    atomicAdd(&deg[d], 1);
}

// Phase A: per-block (256-elem chunk) sums.
__global__ __launch_bounds__(256) void k_scanA(const int* __restrict__ deg, int* __restrict__ bsum)
{
    __shared__ int red[4];
    const int idx = blockIdx.x * 256 + threadIdx.x;
    int v = (idx < N_NODES) ? deg[idx] : 0;
    #pragma unroll
    for (int off = 32; off > 0; off >>= 1) v += __shfl_down(v, off);
    if ((threadIdx.x & 63) == 0) red[threadIdx.x >> 6] = v;
    __syncthreads();
    if (threadIdx.x == 0) bsum[blockIdx.x] = red[0] + red[1] + red[2] + red[3];
}

// Phase B: single-block exclusive scan of SCAN_NB (<=256) partials.
__global__ __launch_bounds__(256) void k_scanB(const int* __restrict__ bsum, int* __restrict__ boff)
{
    __shared__ int part[256];
    const int t = threadIdx.x;
    int v = (t < SCAN_NB) ? bsum[t] : 0;
    part[t] = v;
    __syncthreads();
    #pragma unroll
    for (int d = 1; d < 256; d <<= 1) {
        int add = (t >= d) ? part[t - d] : 0;
        __syncthreads();
        part[t] += add;
        __syncthreads();
    }
    if (t < SCAN_NB) boff[t] = part[t] - v;   // exclusive
}

// Phase C: per-block exclusive scan + block offset -> rowptr, cursor.
__global__ __launch_bounds__(256) void k_scanC(const int* __restrict__ deg,
                                               const int* __restrict__ boff,
                                               int* __restrict__ rowptr, int* __restrict__ cursor)
{
    __shared__ int part[256];
    const int t = threadIdx.x;
    const int idx = blockIdx.x * 256 + t;
    int v = (idx < N_NODES) ? deg[idx] : 0;
    part[t] = v;
    __syncthreads();
    #pragma unroll
    for (int d = 1; d < 256; d <<= 1) {
        int add = (t >= d) ? part[t - d] : 0;
        __syncthreads();
        part[t] += add;
        __syncthreads();
    }
    if (idx < N_NODES) {
        const int p = boff[blockIdx.x] + part[t] - v;
        rowptr[idx] = p; cursor[idx] = p;
    }
    if (idx == 0) rowptr[N_NODES] = ET;       // total degree is a constant
}

__global__ __launch_bounds__(256) void k_scatter(const int* __restrict__ src,
                                                 const int* __restrict__ dst,
                                                 int* __restrict__ cursor,
                                                 int* __restrict__ csr_src)
{
    const int e = blockIdx.x * 256 + threadIdx.x;
    if (e >= ET) return;
    int s, d;
    if (e < N_EDGES) { s = src[e]; d = dst[e]; } else { s = d = e - N_EDGES; }
    const int pos = atomicAdd(&cursor[d], 1);
    csr_src[pos] = s;
}

// ---------------------------------------------------------------------------
// K1: h1 = x @ W1 [N,128] stored as bf16 (only the gather consumes it);
// attention logits as1/ad1 in fp32. 8 nodes / 256-thread block iteration;
// 32 threads per node, 4 channels each, float4 LDS reads of W1.
// ---------------------------------------------------------------------------
__global__ __launch_bounds__(256, 2) void k_gemm1(
    const float* __restrict__ x, const float* __restrict__ W1,
    const float* __restrict__ a_s, const float* __restrict__ a_d,
    unsigned* __restrict__ h1b /* bf16 packed, uint2 view */,
    float* __restrict__ as1, float* __restrict__ ad1)
{
    __shared__ float sW[128 * 128];   // 64 KB
    __shared__ float sx[8][128];      // 4 KB
    const int tid = threadIdx.x;
    for (int i = tid; i < 4096; i += 256) ((float4*)sW)[i] = ((const float4*)W1)[i];
    const int nl = tid >> 5;          // node 0..7
    const int t  = tid & 31;          // 4-channel group: channels 4t..4t+3
    const float4 as4 = ((const float4*)a_s)[t];
    const float4 ad4 = ((const float4*)a_d)[t];
    const int nGroups = N_NODES / 8;  // 6250 exact
    for (int g = blockIdx.x; g < nGroups; g += gridDim.x) {
        const int n0 = g * 8;
        __syncthreads();
        {
            const int node = tid >> 5, quad = tid & 31;
            float4 v = ((const float4*)x)[(n0 + node) * 32 + quad];
            *(float4*)&sx[node][4 * quad] = v;
        }
        __syncthreads();
        float4 sum = {0.f, 0.f, 0.f, 0.f};
        #pragma unroll
        for (int k = 0; k < 128; k++) {
            const float xv = sx[nl][k];
            const float4 w = *(const float4*)&sW[k * 128 + 4 * t];
            sum.x = fmaf(xv, w.x, sum.x);
            sum.y = fmaf(xv, w.y, sum.y);
            sum.z = fmaf(xv, w.z, sum.z);
            sum.w = fmaf(xv, w.w, sum.w);
        }
        const int n = n0 + nl;
        uint2 pk;
        pk.x = f2bf(sum.x) | (f2bf(sum.y) << 16);
        pk.y = f2bf(sum.z) | (f2bf(sum.w) << 16);
        ((uint2*)h1b)[n * 32 + t] = pk;
        float ps = sum.x * as4.x + sum.y * as4.y + sum.z * as4.z + sum.w * as4.w;
        float pd = sum.x * ad4.x + sum.y * ad4.y + sum.z * ad4.z + sum.w * ad4.w;
        #pragma unroll
        for (int off = 1; off < 8; off <<= 1) {
            ps += __shfl_xor(ps, off);
            pd += __shfl_xor(pd, off);
        }
        if ((t & 7) == 0) {
            as1[n * 4 + (t >> 3)] = ps;
            ad1[n * 4 + (t >> 3)] = pd;
        }
    }
}

// ---------------------------------------------------------------------------
// Aggregation layer 1: atomic-free, bf16 gather table, 64 threads/node
// (2 channels per thread via uint), edge loop unrolled x4.
// ---------------------------------------------------------------------------
__global__ __launch_bounds__(256) void k_aggr1(
    const int* __restrict__ rowptr, const int* __restrict__ csr_src,
    const float* __restrict__ as1, const float* __restrict__ ad1,
    const unsigned* __restrict__ h1u, float* __restrict__ acc1)
{
    const int d  = blockIdx.x * 4 + (threadIdx.x >> 6);
    const int c2 = threadIdx.x & 63;    // channels 2*c2, 2*c2+1
    const int hd = c2 >> 4;
    const int r0 = rowptr[d], r1 = rowptr[d + 1];
    const float adv = ad1[d * 4 + hd];
    float den = 0.f, alo = 0.f, ahi = 0.f;
    int i = r0;
    for (; i + 4 <= r1; i += 4) {
        const int s0 = csr_src[i + 0], s1 = csr_src[i + 1];
        const int s2 = csr_src[i + 2], s3 = csr_src[i + 3];
        const float e0 = as1[s0 * 4 + hd], e1 = as1[s1 * 4 + hd];
        const float e2 = as1[s2 * 4 + hd], e3 = as1[s3 * 4 + hd];
        const unsigned u0 = h1u[s0 * 64 + c2], u1 = h1u[s1 * 64 + c2];
        const unsigned u2 = h1u[s2 * 64 + c2], u3 = h1u[s3 * 64 + c2];
        const float w0 = expf(lrelu(e0 + adv));
        const float w1 = expf(lrelu(e1 + adv));
        const float w2 = expf(lrelu(e2 + adv));
        const float w3 = expf(lrelu(e3 + adv));
        den += (w0 + w1) + (w2 + w3);
        alo = fmaf(bflo(u0), w0, alo); ahi = fmaf(bfhi(u0), w0, ahi);
        alo = fmaf(bflo(u1), w1, alo); ahi = fmaf(bfhi(u1), w1, ahi);
        alo = fmaf(bflo(u2), w2, alo); ahi = fmaf(bfhi(u2), w2, ahi);
        alo = fmaf(bflo(u3), w3, alo); ahi = fmaf(bfhi(u3), w3, ahi);
    }
    for (; i < r1; i++) {
        const int s = csr_src[i];
        const float w = expf(lrelu(as1[s * 4 + hd] + adv));
        const unsigned u = h1u[s * 64 + c2];
        den += w;
        alo = fmaf(bflo(u), w, alo);
        ahi = fmaf(bfhi(u), w, ahi);
    }
    const float inv = 1.f / (den + 1e-16f);
    *(float2*)&acc1[d * 128 + 2 * c2] = make_float2(alo * inv, ahi * inv);
}

// ---------------------------------------------------------------------------
// K4: hE = elu(acc1+b1); h2 = hE @ W2 [N,64] stored bf16; logits as2/ad2 fp32.
// 16 nodes / block iteration; 16 threads per node, 4 channels each.
// ---------------------------------------------------------------------------
__global__ __launch_bounds__(256, 2) void k_layer2(
    const float* __restrict__ acc1, const float* __restrict__ b1,
    const float* __restrict__ W2, const float* __restrict__ a_s2, const float* __restrict__ a_d2,
    unsigned* __restrict__ h2b, float* __restrict__ as2, float* __restrict__ ad2)
{
    __shared__ float sW[128 * 64];    // 32 KB
    __shared__ float sh[16][128];     // 8 KB
    const int tid = threadIdx.x;
    for (int i = tid; i < 2048; i += 256) ((float4*)sW)[i] = ((const float4*)W2)[i];
    const int nl = tid >> 4;          // node 0..15
    const int t  = tid & 15;          // channels 4t..4t+3
    const float4 as4 = ((const float4*)a_s2)[t];
    const float4 ad4 = ((const float4*)a_d2)[t];
    const int nGroups = N_NODES / 16; // 3125 exact
    for (int g = blockIdx.x; g < nGroups; g += gridDim.x) {
        const int n0 = g * 16;
        __syncthreads();
        #pragma unroll
        for (int i = tid; i < 512; i += 256) {
            const int node = i >> 5, quad = i & 31;
            float4 v = ((const float4*)acc1)[(n0 + node) * 32 + quad];
            const float4 bb = ((const float4*)b1)[quad];
            v.x = eluf(v.x + bb.x);
            v.y = eluf(v.y + bb.y);
            v.z = eluf(v.z + bb.z);
            v.w = eluf(v.w + bb.w);
            *(float4*)&sh[node][4 * quad] = v;
        }
        __syncthreads();
        float4 sum = {0.f, 0.f, 0.f, 0.f};
        #pragma unroll
        for (int k = 0; k < 128; k++) {
            const float xv = sh[nl][k];
            const float4 w = *(const float4*)&sW[k * 64 + 4 * t];
            sum.x = fmaf(xv, w.x, sum.x);
            sum.y = fmaf(xv, w.y, sum.y);
            sum.z = fmaf(xv, w.z, sum.z);
            sum.w = fmaf(xv, w.w, sum.w);
        }
        const int n = n0 + nl;
        uint2 pk;
        pk.x = f2bf(sum.x) | (f2bf(sum.y) << 16);
        pk.y = f2bf(sum.z) | (f2bf(sum.w) << 16);
        ((uint2*)h2b)[n * 16 + t] = pk;
        float ps = sum.x * as4.x + sum.y * as4.y + sum.z * as4.z + sum.w * as4.w;
        float pd = sum.x * ad4.x + sum.y * ad4.y + sum.z * ad4.z + sum.w * ad4.w;
        #pragma unroll
        for (int off = 1; off < 16; off <<= 1) {
            ps += __shfl_xor(ps, off);
            pd += __shfl_xor(pd, off);
        }
        if (t == 0) { as2[n] = ps; ad2[n] = pd; }
    }
}

// ---------------------------------------------------------------------------
// Aggregation layer 2 (1 head): 32 threads/node (2 bf16 ch per thread).
// ---------------------------------------------------------------------------
__global__ __launch_bounds__(256) void k_aggr2(
    const int* __restrict__ rowptr, const int* __restrict__ csr_src,
    const float* __restrict__ as2, const float* __restrict__ ad2,
    const unsigned* __restrict__ h2u, float* __restrict__ acc2)
{
    const int d  = blockIdx.x * 8 + (threadIdx.x >> 5);
    const int c2 = threadIdx.x & 31;
    const int r0 = rowptr[d], r1 = rowptr[d + 1];
    const float adv = ad2[d];
    float den = 0.f, alo = 0.f, ahi = 0.f;
    int i = r0;
    for (; i + 4 <= r1; i += 4) {
        const int s0 = csr_src[i + 0], s1 = csr_src[i + 1];
        const int s2 = csr_src[i + 2], s3 = csr_src[i + 3];
        const float e0 = as2[s0], e1 = as2[s1], e2 = as2[s2], e3 = as2[s3];
        const unsigned u0 = h2u[s0 * 32 + c2], u1 = h2u[s1 * 32 + c2];
        const unsigned u2 = h2u[s2 * 32 + c2], u3 = h2u[s3 * 32 + c2];
        const float w0 = expf(lrelu(e0 + adv));
        const float w1 = expf(lrelu(e1 + adv));
        const float w2 = expf(lrelu(e2 + adv));
        const float w3 = expf(lrelu(e3 + adv));
        den += (w0 + w1) + (w2 + w3);
        alo = fmaf(bflo(u0), w0, alo); ahi = fmaf(bfhi(u0), w0, ahi);
        alo = fmaf(bflo(u1), w1, alo); ahi = fmaf(bfhi(u1), w1, ahi);
        alo = fmaf(bflo(u2), w2, alo); ahi = fmaf(bfhi(u2), w2, ahi);
        alo = fmaf(bflo(u3), w3, alo); ahi = fmaf(bfhi(u3), w3, ahi);
    }
    for (; i < r1; i++) {
        const int s = csr_src[i];
        const float w = expf(lrelu(as2[s] + adv));
        const unsigned u = h2u[s * 32 + c2];
        den += w;
        alo = fmaf(bflo(u), w, alo);
        ahi = fmaf(bfhi(u), w, ahi);
    }
    const float inv = 1.f / (den + 1e-16f);
    *(float2*)&acc2[d * 64 + 2 * c2] = make_float2(alo * inv, ahi * inv);
}

// ---------------------------------------------------------------------------
// K7: o = elu(acc2+b2); p = relu(o@pw1+pb1); out = p@pw2+pb2.
// 16 nodes / block iteration; 16 threads/node, 4 channels each, float4 LDS.
// ---------------------------------------------------------------------------
__global__ __launch_bounds__(256, 2) void k_out(
    const float* __restrict__ acc2, const float* __restrict__ b2,
    const float* __restrict__ pw1, const float* __restrict__ pb1,
    const float* __restrict__ pw2, const float* __restrict__ pb2,
    float* __restrict__ out)
{
    __shared__ float s1[64 * 64];
    __shared__ float s2[64 * 64];
    __shared__ float so[16][64];
    __shared__ float sp[16][64];
    const int tid = threadIdx.x;
    for (int i = tid; i < 1024; i += 256) {
        ((float4*)s1)[i] = ((const float4*)pw1)[i];
        ((float4*)s2)[i] = ((const float4*)pw2)[i];
    }
    const int nl = tid >> 4, t = tid & 15;
    const float4 b2_4  = ((const float4*)b2)[t];
    const float4 pb1_4 = ((const float4*)pb1)[t];
    const float4 pb2_4 = ((const float4*)pb2)[t];
    const int nGroups = N_NODES / 16;   // 3125
    for (int g = blockIdx.x; g < nGroups; g += gridDim.x) {
        const int n = g * 16 + nl;
        __syncthreads();
        {
            float4 v = ((const float4*)acc2)[n * 16 + t];
            v.x = eluf(v.x + b2_4.x);
            v.y = eluf(v.y + b2_4.y);
            v.z = eluf(v.z + b2_4.z);
            v.w = eluf(v.w + b2_4.w);
            *(float4*)&so[nl][4 * t] = v;
        }
        __syncthreads();
        float4 p = pb1_4;
        #pragma unroll
        for (int k = 0; k < 64; k++) {
            const float xv = so[nl][k];
            const float4 w = *(const float4*)&s1[k * 64 + 4 * t];
            p.x = fmaf(xv, w.x, p.x);
            p.y = fmaf(xv, w.y, p.y);
            p.z = fmaf(xv, w.z, p.z);
            p.w = fmaf(xv, w.w, p.w);
        }
        p.x = fmaxf(p.x, 0.f); p.y = fmaxf(p.y, 0.f);
        p.z = fmaxf(p.z, 0.f); p.w = fmaxf(p.w, 0.f);
        *(float4*)&sp[nl][4 * t] = p;
        __syncthreads();
        float4 o = pb2_4;
        #pragma unroll
        for (int k = 0; k < 64; k++) {
            const float xv = sp[nl][k];
            const float4 w = *(const float4*)&s2[k * 64 + 4 * t];
            o.x = fmaf(xv, w.x, o.x);
            o.y = fmaf(xv, w.y, o.y);
            o.z = fmaf(xv, w.z, o.z);
            o.w = fmaf(xv, w.w, o.w);
        }
        ((float4*)out)[n * 16 + t] = o;
    }
}

// ---------------------------------------------------------------------------
extern "C" void kernel_launch(void* const* d_in, const int* in_sizes, int n_in,
                              void* d_out, int out_size, void* d_ws, size_t ws_size,
                              hipStream_t stream)
{
    const float* x      = (const float*)d_in[0];
    const int*   ei     = (const int*)d_in[1];   // [2, E] int32
    const int*   src    = ei;
    const int*   dst    = ei + N_EDGES;
    const float* W1     = (const float*)d_in[2];
    const float* a_src1 = (const float*)d_in[3];
    const float* a_dst1 = (const float*)d_in[4];
    const float* b1     = (const float*)d_in[5];
    const float* W2     = (const float*)d_in[6];
    const float* a_src2 = (const float*)d_in[7];
    const float* a_dst2 = (const float*)d_in[8];
    const float* b2     = (const float*)d_in[9];
    const float* pw1    = (const float*)d_in[10];
    const float* pb1    = (const float*)d_in[11];
    const float* pw2    = (const float*)d_in[12];
    const float* pb2    = (const float*)d_in[13];

    // Workspace layout.
    int* deg     = (int*)d_ws;            // 50,000
    int* rowptr  = deg + 50000;           // 50,001
    int* cursor  = rowptr + 50001;        // 50,000
    int* bsum    = cursor + 50000;        // 256
    int* boff    = bsum + 256;            // 256
    int* csr_src = boff + 256;            // 850,000
    unsigned* h1b = (unsigned*)(csr_src + 850000);  // N*64 uints (bf16 x2) = 3,200,000
    unsigned* h2b = h1b + 3200000;                  // N*32 uints           = 1,600,000
    float* fws   = (float*)(h2b + 1600000);
    float* as1   = fws;                   // N*4
    float* ad1   = as1 + 200000;          // N*4
    float* acc1  = ad1 + 200000;          // N*128 = 6,400,000
    float* as2   = acc1 + 6400000;        // N
    float* ad2   = as2 + 50000;           // N
    float* acc2  = ad2 + 50000;           // N*64  = 3,200,000
    // total ~ 62 MB

    // CSR build (reused by both layers)
    hipMemsetAsync(deg, 0, 50000 * sizeof(int), stream);
    k_hist<<<(ET + 255) / 256, 256, 0, stream>>>(dst, deg);
    k_scanA<<<SCAN_NB, 256, 0, stream>>>(deg, bsum);
    k_scanB<<<1, 256, 0, stream>>>(bsum, boff);
    k_scanC<<<SCAN_NB, 256, 0, stream>>>(deg, boff, rowptr, cursor);
    k_scatter<<<(ET + 255) / 256, 256, 0, stream>>>(src, dst, cursor, csr_src);

    // Layer 1
    k_gemm1<<<2048, 256, 0, stream>>>(x, W1, a_src1, a_dst1, h1b, as1, ad1);
    k_aggr1<<<N_NODES / 4, 256, 0, stream>>>(rowptr, csr_src, as1, ad1, h1b, acc1);

    // Layer 2
    k_layer2<<<2048, 256, 0, stream>>>(acc1, b1, W2, a_src2, a_dst2, h2b, as2, ad2);
    k_aggr2<<<N_NODES / 8, 256, 0, stream>>>(rowptr, csr_src, as2, ad2, h2b, acc2);

    // Output MLP
    k_out<<<2048, 256, 0, stream>>>(acc2, b2, pw1, pb1, pw2, pb2, (float*)d_out);
}

// Round 5
// 360.300 us; speedup vs baseline: 2.9529x; 1.0348x over previous
//
#include <hip/hip_runtime.h>
#include <math.h>

// Problem constants (from reference)
#define N_NODES 50000
#define N_EDGES 800000
#define ET (N_EDGES + N_NODES)   // edges + self loops = 850000
#define IN_DIM 128
#define HID 128
#define OUT_DIM 64
#define SCAN_NB ((N_NODES + 255) / 256)   // 196 scan blocks

__device__ __forceinline__ float lrelu(float x){ return x >= 0.f ? x : 0.2f * x; }
__device__ __forceinline__ float eluf(float x){ return x > 0.f ? x : expm1f(x); }
// RNE float->bf16 (finite inputs)
__device__ __forceinline__ unsigned f2bf(float f){
    unsigned u = __float_as_uint(f);
    return (u + 0x7fffu + ((u >> 16) & 1u)) >> 16;
}
__device__ __forceinline__ float bflo(unsigned u){ return __uint_as_float(u << 16); }
__device__ __forceinline__ float bfhi(unsigned u){ return __uint_as_float(u & 0xffff0000u); }

// ---------------------------------------------------------------------------
// CSR build: histogram -> hierarchical 3-phase scan -> scatter.
// ---------------------------------------------------------------------------
__global__ __launch_bounds__(256) void k_hist(const int* __restrict__ dst, int* __restrict__ deg)
{
    const int e = blockIdx.x * 256 + threadIdx.x;
    if (e >= ET) return;
    const int d = (e < N_EDGES) ? dst[e] : (e - N_EDGES);
    atomicAdd(&deg[d], 1);
}

__global__ __launch_bounds__(256) void k_scanA(const int* __restrict__ deg, int* __restrict__ bsum)
{
    __shared__ int red[4];
    const int idx = blockIdx.x * 256 + threadIdx.x;
    int v = (idx < N_NODES) ? deg[idx] : 0;
    #pragma unroll
    for (int off = 32; off > 0; off >>= 1) v += __shfl_down(v, off);
    if ((threadIdx.x & 63) == 0) red[threadIdx.x >> 6] = v;
    __syncthreads();
    if (threadIdx.x == 0) bsum[blockIdx.x] = red[0] + red[1] + red[2] + red[3];
}

__global__ __launch_bounds__(256) void k_scanB(const int* __restrict__ bsum, int* __restrict__ boff)
{
    __shared__ int part[256];
    const int t = threadIdx.x;
    int v = (t < SCAN_NB) ? bsum[t] : 0;
    part[t] = v;
    __syncthreads();
    #pragma unroll
    for (int d = 1; d < 256; d <<= 1) {
        int add = (t >= d) ? part[t - d] : 0;
        __syncthreads();
        part[t] += add;
        __syncthreads();
    }
    if (t < SCAN_NB) boff[t] = part[t] - v;   // exclusive
}

__global__ __launch_bounds__(256) void k_scanC(const int* __restrict__ deg,
                                               const int* __restrict__ boff,
                                               int* __restrict__ rowptr, int* __restrict__ cursor)
{
    __shared__ int part[256];
    const int t = threadIdx.x;
    const int idx = blockIdx.x * 256 + t;
    int v = (idx < N_NODES) ? deg[idx] : 0;
    part[t] = v;
    __syncthreads();
    #pragma unroll
    for (int d = 1; d < 256; d <<= 1) {
        int add = (t >= d) ? part[t - d] : 0;
        __syncthreads();
        part[t] += add;
        __syncthreads();
    }
    if (idx < N_NODES) {
        const int p = boff[blockIdx.x] + part[t] - v;
        rowptr[idx] = p; cursor[idx] = p;
    }
    if (idx == 0) rowptr[N_NODES] = ET;
}

__global__ __launch_bounds__(256) void k_scatter(const int* __restrict__ src,
                                                 const int* __restrict__ dst,
                                                 int* __restrict__ cursor,
                                                 int* __restrict__ csr_src)
{
    const int e = blockIdx.x * 256 + threadIdx.x;
    if (e >= ET) return;
    int s, d;
    if (e < N_EDGES) { s = src[e]; d = dst[e]; } else { s = d = e - N_EDGES; }
    const int pos = atomicAdd(&cursor[d], 1);
    csr_src[pos] = s;
}

// ---------------------------------------------------------------------------
// K1: h1 = x @ W1 [N,128] -> bf16 table + fp32 logits.
// Register-blocked: 32 nodes/iter, each thread 4 nodes x 4 channels (16 FMA
// per W float4). sW 64KB + sx 16KB = 80KB -> 2 blocks/CU.
// sx scalar reads: wave spans 2 node-groups -> 2-addr broadcast (free).
// ---------------------------------------------------------------------------
__global__ __launch_bounds__(256, 2) void k_gemm1(
    const float* __restrict__ x, const float* __restrict__ W1,
    const float* __restrict__ a_s, const float* __restrict__ a_d,
    unsigned* __restrict__ h1b, float* __restrict__ as1, float* __restrict__ ad1)
{
    __shared__ float sW[128 * 128];   // 64 KB
    __shared__ float sx[32][128];     // 16 KB
    const int tid = threadIdx.x;
    for (int i = tid; i < 4096; i += 256) ((float4*)sW)[i] = ((const float4*)W1)[i];
    const int cg = tid & 31;          // channels 4cg..4cg+3
    const int ng = tid >> 5;          // node group 0..7 (nodes 4ng..4ng+3)
    const float4 as4 = ((const float4*)a_s)[cg];
    const float4 ad4 = ((const float4*)a_d)[cg];
    const int nGroups = (N_NODES + 31) / 32;   // 1563
    for (int g = blockIdx.x; g < nGroups; g += gridDim.x) {
        const int n0 = g * 32;
        __syncthreads();
        #pragma unroll
        for (int j = 0; j < 4; j++) {
            const int i = tid + 256 * j;
            const int node = i >> 5, quad = i & 31;
            const int n = n0 + node;
            float4 v = make_float4(0.f, 0.f, 0.f, 0.f);
            if (n < N_NODES) v = ((const float4*)x)[n * 32 + quad];
            *(float4*)&sx[node][4 * quad] = v;
        }
        __syncthreads();
        float4 acc[4];
        #pragma unroll
        for (int m = 0; m < 4; m++) acc[m] = make_float4(0.f, 0.f, 0.f, 0.f);
        #pragma unroll 8
        for (int k = 0; k < 128; k++) {
            const float4 w = *(const float4*)&sW[k * 128 + 4 * cg];
            #pragma unroll
            for (int m = 0; m < 4; m++) {
                const float xv = sx[4 * ng + m][k];
                acc[m].x = fmaf(xv, w.x, acc[m].x);
                acc[m].y = fmaf(xv, w.y, acc[m].y);
                acc[m].z = fmaf(xv, w.z, acc[m].z);
                acc[m].w = fmaf(xv, w.w, acc[m].w);
            }
        }
        #pragma unroll
        for (int m = 0; m < 4; m++) {
            const int n = n0 + 4 * ng + m;
            float ps = acc[m].x * as4.x + acc[m].y * as4.y + acc[m].z * as4.z + acc[m].w * as4.w;
            float pd = acc[m].x * ad4.x + acc[m].y * ad4.y + acc[m].z * ad4.z + acc[m].w * ad4.w;
            #pragma unroll
            for (int off = 1; off < 8; off <<= 1) {
                ps += __shfl_xor(ps, off);
                pd += __shfl_xor(pd, off);
            }
            if (n < N_NODES) {
                uint2 pk;
                pk.x = f2bf(acc[m].x) | (f2bf(acc[m].y) << 16);
                pk.y = f2bf(acc[m].z) | (f2bf(acc[m].w) << 16);
                ((uint2*)h1b)[n * 32 + cg] = pk;
                if ((cg & 7) == 0) {
                    as1[n * 4 + (cg >> 3)] = ps;
                    ad1[n * 4 + (cg >> 3)] = pd;
                }
            }
        }
    }
}

// ---------------------------------------------------------------------------
// Aggregation layer 1: atomic-free, bf16 gather table, 64 threads/node.
// ---------------------------------------------------------------------------
__global__ __launch_bounds__(256) void k_aggr1(
    const int* __restrict__ rowptr, const int* __restrict__ csr_src,
    const float* __restrict__ as1, const float* __restrict__ ad1,
    const unsigned* __restrict__ h1u, float* __restrict__ acc1)
{
    const int d  = blockIdx.x * 4 + (threadIdx.x >> 6);
    const int c2 = threadIdx.x & 63;    // channels 2*c2, 2*c2+1
    const int hd = c2 >> 4;
    const int r0 = rowptr[d], r1 = rowptr[d + 1];
    const float adv = ad1[d * 4 + hd];
    float den = 0.f, alo = 0.f, ahi = 0.f;
    int i = r0;
    for (; i + 4 <= r1; i += 4) {
        const int s0 = csr_src[i + 0], s1 = csr_src[i + 1];
        const int s2 = csr_src[i + 2], s3 = csr_src[i + 3];
        const float e0 = as1[s0 * 4 + hd], e1 = as1[s1 * 4 + hd];
        const float e2 = as1[s2 * 4 + hd], e3 = as1[s3 * 4 + hd];
        const unsigned u0 = h1u[s0 * 64 + c2], u1 = h1u[s1 * 64 + c2];
        const unsigned u2 = h1u[s2 * 64 + c2], u3 = h1u[s3 * 64 + c2];
        const float w0 = expf(lrelu(e0 + adv));
        const float w1 = expf(lrelu(e1 + adv));
        const float w2 = expf(lrelu(e2 + adv));
        const float w3 = expf(lrelu(e3 + adv));
        den += (w0 + w1) + (w2 + w3);
        alo = fmaf(bflo(u0), w0, alo); ahi = fmaf(bfhi(u0), w0, ahi);
        alo = fmaf(bflo(u1), w1, alo); ahi = fmaf(bfhi(u1), w1, ahi);
        alo = fmaf(bflo(u2), w2, alo); ahi = fmaf(bfhi(u2), w2, ahi);
        alo = fmaf(bflo(u3), w3, alo); ahi = fmaf(bfhi(u3), w3, ahi);
    }
    for (; i < r1; i++) {
        const int s = csr_src[i];
        const float w = expf(lrelu(as1[s * 4 + hd] + adv));
        const unsigned u = h1u[s * 64 + c2];
        den += w;
        alo = fmaf(bflo(u), w, alo);
        ahi = fmaf(bfhi(u), w, ahi);
    }
    const float inv = 1.f / (den + 1e-16f);
    *(float2*)&acc1[d * 128 + 2 * c2] = make_float2(alo * inv, ahi * inv);
}

// ---------------------------------------------------------------------------
// K4: hE = elu(acc1+b1); h2 = hE @ W2 [N,64] -> bf16 table + fp32 logits.
// Register-blocked: 64 nodes/iter, thread = 4 nodes x 4 channels.
// sh padded to 132 floats/row: scalar-read bank = (4*node+k)%32 -> 2-way max.
// sW 32KB + sh 33.8KB -> 2 blocks/CU.
// ---------------------------------------------------------------------------
__global__ __launch_bounds__(256, 2) void k_layer2(
    const float* __restrict__ acc1, const float* __restrict__ b1,
    const float* __restrict__ W2, const float* __restrict__ a_s2, const float* __restrict__ a_d2,
    unsigned* __restrict__ h2b, float* __restrict__ as2, float* __restrict__ ad2)
{
    __shared__ float sW[128 * 64];    // 32 KB
    __shared__ float sh[64][132];     // 33.8 KB (pad 4 keeps float4 align)
    const int tid = threadIdx.x;
    for (int i = tid; i < 2048; i += 256) ((float4*)sW)[i] = ((const float4*)W2)[i];
    const int cg = tid & 15;          // channels 4cg..4cg+3
    const int ng = tid >> 4;          // node group 0..15
    const float4 as4 = ((const float4*)a_s2)[cg];
    const float4 ad4 = ((const float4*)a_d2)[cg];
    const int nGroups = (N_NODES + 63) / 64;   // 782
    for (int g = blockIdx.x; g < nGroups; g += gridDim.x) {
        const int n0 = g * 64;
        __syncthreads();
        #pragma unroll
        for (int j = 0; j < 8; j++) {
            const int i = tid + 256 * j;
            const int node = i >> 5, quad = i & 31;
            const int n = n0 + node;
            float4 v = make_float4(0.f, 0.f, 0.f, 0.f);
            if (n < N_NODES) {
                v = ((const float4*)acc1)[n * 32 + quad];
                const float4 bb = ((const float4*)b1)[quad];
                v.x = eluf(v.x + bb.x);
                v.y = eluf(v.y + bb.y);
                v.z = eluf(v.z + bb.z);
                v.w = eluf(v.w + bb.w);
            }
            *(float4*)&sh[node][4 * quad] = v;
        }
        __syncthreads();
        float4 acc[4];
        #pragma unroll
        for (int m = 0; m < 4; m++) acc[m] = make_float4(0.f, 0.f, 0.f, 0.f);
        #pragma unroll 8
        for (int k = 0; k < 128; k++) {
            const float4 w = *(const float4*)&sW[k * 64 + 4 * cg];
            #pragma unroll
            for (int m = 0; m < 4; m++) {
                const float xv = sh[4 * ng + m][k];
                acc[m].x = fmaf(xv, w.x, acc[m].x);
                acc[m].y = fmaf(xv, w.y, acc[m].y);
                acc[m].z = fmaf(xv, w.z, acc[m].z);
                acc[m].w = fmaf(xv, w.w, acc[m].w);
            }
        }
        #pragma unroll
        for (int m = 0; m < 4; m++) {
            const int n = n0 + 4 * ng + m;
            float ps = acc[m].x * as4.x + acc[m].y * as4.y + acc[m].z * as4.z + acc[m].w * as4.w;
            float pd = acc[m].x * ad4.x + acc[m].y * ad4.y + acc[m].z * ad4.z + acc[m].w * ad4.w;
            #pragma unroll
            for (int off = 1; off < 16; off <<= 1) {
                ps += __shfl_xor(ps, off);
                pd += __shfl_xor(pd, off);
            }
            if (n < N_NODES) {
                uint2 pk;
                pk.x = f2bf(acc[m].x) | (f2bf(acc[m].y) << 16);
                pk.y = f2bf(acc[m].z) | (f2bf(acc[m].w) << 16);
                ((uint2*)h2b)[n * 16 + cg] = pk;
                if (cg == 0) { as2[n] = ps; ad2[n] = pd; }
            }
        }
    }
}

// ---------------------------------------------------------------------------
// Aggregation layer 2 (1 head): 32 threads/node (2 bf16 ch per thread).
// ---------------------------------------------------------------------------
__global__ __launch_bounds__(256) void k_aggr2(
    const int* __restrict__ rowptr, const int* __restrict__ csr_src,
    const float* __restrict__ as2, const float* __restrict__ ad2,
    const unsigned* __restrict__ h2u, float* __restrict__ acc2)
{
    const int d  = blockIdx.x * 8 + (threadIdx.x >> 5);
    const int c2 = threadIdx.x & 31;
    const int r0 = rowptr[d], r1 = rowptr[d + 1];
    const float adv = ad2[d];
    float den = 0.f, alo = 0.f, ahi = 0.f;
    int i = r0;
    for (; i + 4 <= r1; i += 4) {
        const int s0 = csr_src[i + 0], s1 = csr_src[i + 1];
        const int s2 = csr_src[i + 2], s3 = csr_src[i + 3];
        const float e0 = as2[s0], e1 = as2[s1], e2 = as2[s2], e3 = as2[s3];
        const unsigned u0 = h2u[s0 * 32 + c2], u1 = h2u[s1 * 32 + c2];
        const unsigned u2 = h2u[s2 * 32 + c2], u3 = h2u[s3 * 32 + c2];
        const float w0 = expf(lrelu(e0 + adv));
        const float w1 = expf(lrelu(e1 + adv));
        const float w2 = expf(lrelu(e2 + adv));
        const float w3 = expf(lrelu(e3 + adv));
        den += (w0 + w1) + (w2 + w3);
        alo = fmaf(bflo(u0), w0, alo); ahi = fmaf(bfhi(u0), w0, ahi);
        alo = fmaf(bflo(u1), w1, alo); ahi = fmaf(bfhi(u1), w1, ahi);
        alo = fmaf(bflo(u2), w2, alo); ahi = fmaf(bfhi(u2), w2, ahi);
        alo = fmaf(bflo(u3), w3, alo); ahi = fmaf(bfhi(u3), w3, ahi);
    }
    for (; i < r1; i++) {
        const int s = csr_src[i];
        const float w = expf(lrelu(as2[s] + adv));
        const unsigned u = h2u[s * 32 + c2];
        den += w;
        alo = fmaf(bflo(u), w, alo);
        ahi = fmaf(bfhi(u), w, ahi);
    }
    const float inv = 1.f / (den + 1e-16f);
    *(float2*)&acc2[d * 64 + 2 * c2] = make_float2(alo * inv, ahi * inv);
}

// ---------------------------------------------------------------------------
// K7: o = elu(acc2+b2); p = relu(o@pw1+pb1); out = p@pw2+pb2.
// Register-blocked: 64 nodes/iter, thread = 4 nodes x 4 channels per GEMM.
// s1+s2 32KB + so/sp (68-pad) 34.8KB -> 2 blocks/CU.
// ---------------------------------------------------------------------------
__global__ __launch_bounds__(256, 2) void k_out(
    const float* __restrict__ acc2, const float* __restrict__ b2,
    const float* __restrict__ pw1, const float* __restrict__ pb1,
    const float* __restrict__ pw2, const float* __restrict__ pb2,
    float* __restrict__ out)
{
    __shared__ float s1[64 * 64];     // 16 KB
    __shared__ float s2[64 * 64];     // 16 KB
    __shared__ float so[64][68];      // 17.4 KB
    __shared__ float sp[64][68];      // 17.4 KB
    const int tid = threadIdx.x;
    for (int i = tid; i < 1024; i += 256) {
        ((float4*)s1)[i] = ((const float4*)pw1)[i];
        ((float4*)s2)[i] = ((const float4*)pw2)[i];
    }
    const int cg = tid & 15;          // channels 4cg..4cg+3
    const int ng = tid >> 4;          // node group 0..15
    const float4 pb1_4 = ((const float4*)pb1)[cg];
    const float4 pb2_4 = ((const float4*)pb2)[cg];
    const int nGroups = (N_NODES + 63) / 64;   // 782
    for (int g = blockIdx.x; g < nGroups; g += gridDim.x) {
        const int n0 = g * 64;
        __syncthreads();
        #pragma unroll
        for (int j = 0; j < 4; j++) {
            const int i = tid + 256 * j;
            const int node = i >> 4, quad = i & 15;
            const int n = n0 + node;
            float4 v = make_float4(0.f, 0.f, 0.f, 0.f);
            if (n < N_NODES) {
                v = ((const float4*)acc2)[n * 16 + quad];
                const float4 bb = ((const float4*)b2)[quad];
                v.x = eluf(v.x + bb.x);
                v.y = eluf(v.y + bb.y);
                v.z = eluf(v.z + bb.z);
                v.w = eluf(v.w + bb.w);
            }
            *(float4*)&so[node][4 * quad] = v;
        }
        __syncthreads();
        float4 p[4];
        #pragma unroll
        for (int m = 0; m < 4; m++) p[m] = pb1_4;
        #pragma unroll 8
        for (int k = 0; k < 64; k++) {
            const float4 w = *(const float4*)&s1[k * 64 + 4 * cg];
            #pragma unroll
            for (int m = 0; m < 4; m++) {
                const float xv = so[4 * ng + m][k];
                p[m].x = fmaf(xv, w.x, p[m].x);
                p[m].y = fmaf(xv, w.y, p[m].y);
                p[m].z = fmaf(xv, w.z, p[m].z);
                p[m].w = fmaf(xv, w.w, p[m].w);
            }
        }
        #pragma unroll
        for (int m = 0; m < 4; m++) {
            p[m].x = fmaxf(p[m].x, 0.f); p[m].y = fmaxf(p[m].y, 0.f);
            p[m].z = fmaxf(p[m].z, 0.f); p[m].w = fmaxf(p[m].w, 0.f);
            *(float4*)&sp[4 * ng + m][4 * cg] = p[m];
        }
        __syncthreads();
        float4 o[4];
        #pragma unroll
        for (int m = 0; m < 4; m++) o[m] = pb2_4;
        #pragma unroll 8
        for (int k = 0; k < 64; k++) {
            const float4 w = *(const float4*)&s2[k * 64 + 4 * cg];
            #pragma unroll
            for (int m = 0; m < 4; m++) {
                const float xv = sp[4 * ng + m][k];
                o[m].x = fmaf(xv, w.x, o[m].x);
                o[m].y = fmaf(xv, w.y, o[m].y);
                o[m].z = fmaf(xv, w.z, o[m].z);
                o[m].w = fmaf(xv, w.w, o[m].w);
            }
        }
        #pragma unroll
        for (int m = 0; m < 4; m++) {
            const int n = n0 + 4 * ng + m;
            if (n < N_NODES) ((float4*)out)[n * 16 + cg] = o[m];
        }
    }
}

// ---------------------------------------------------------------------------
extern "C" void kernel_launch(void* const* d_in, const int* in_sizes, int n_in,
                              void* d_out, int out_size, void* d_ws, size_t ws_size,
                              hipStream_t stream)
{
    const float* x      = (const float*)d_in[0];
    const int*   ei     = (const int*)d_in[1];   // [2, E] int32
    const int*   src    = ei;
    const int*   dst    = ei + N_EDGES;
    const float* W1     = (const float*)d_in[2];
    const float* a_src1 = (const float*)d_in[3];
    const float* a_dst1 = (const float*)d_in[4];
    const float* b1     = (const float*)d_in[5];
    const float* W2     = (const float*)d_in[6];
    const float* a_src2 = (const float*)d_in[7];
    const float* a_dst2 = (const float*)d_in[8];
    const float* b2     = (const float*)d_in[9];
    const float* pw1    = (const float*)d_in[10];
    const float* pb1    = (const float*)d_in[11];
    const float* pw2    = (const float*)d_in[12];
    const float* pb2    = (const float*)d_in[13];

    // Workspace layout.
    int* deg     = (int*)d_ws;            // 50,000
    int* rowptr  = deg + 50000;           // 50,001
    int* cursor  = rowptr + 50001;        // 50,000
    int* bsum    = cursor + 50000;        // 256
    int* boff    = bsum + 256;            // 256
    int* csr_src = boff + 256;            // 850,000
    unsigned* h1b = (unsigned*)(csr_src + 850000);  // N*64 uints (bf16 x2)
    unsigned* h2b = h1b + 3200000;                  // N*32 uints
    float* fws   = (float*)(h2b + 1600000);
    float* as1   = fws;                   // N*4
    float* ad1   = as1 + 200000;          // N*4
    float* acc1  = ad1 + 200000;          // N*128
    float* as2   = acc1 + 6400000;        // N
    float* ad2   = as2 + 50000;           // N
    float* acc2  = ad2 + 50000;           // N*64
    // total ~ 62 MB

    // CSR build (reused by both layers)
    hipMemsetAsync(deg, 0, 50000 * sizeof(int), stream);
    k_hist<<<(ET + 255) / 256, 256, 0, stream>>>(dst, deg);
    k_scanA<<<SCAN_NB, 256, 0, stream>>>(deg, bsum);
    k_scanB<<<1, 256, 0, stream>>>(bsum, boff);
    k_scanC<<<SCAN_NB, 256, 0, stream>>>(deg, boff, rowptr, cursor);
    k_scatter<<<(ET + 255) / 256, 256, 0, stream>>>(src, dst, cursor, csr_src);

    // Layer 1
    k_gemm1<<<1563, 256, 0, stream>>>(x, W1, a_src1, a_dst1, h1b, as1, ad1);
    k_aggr1<<<N_NODES / 4, 256, 0, stream>>>(rowptr, csr_src, as1, ad1, h1b, acc1);

    // Layer 2
    k_layer2<<<782, 256, 0, stream>>>(acc1, b1, W2, a_src2, a_dst2, h2b, as2, ad2);
    k_aggr2<<<N_NODES / 8, 256, 0, stream>>>(rowptr, csr_src, as2, ad2, h2b, acc2);

    // Output MLP
    k_out<<<782, 256, 0, stream>>>(acc2, b2, pw1, pb1, pw2, pb2, (float*)d_out);
}